// Round 3
// baseline (224.476 us; speedup 1.0000x reference)
//
#include <hip/hip_runtime.h>
#include <hip/hip_bf16.h>

// 64-point complex FFT + fftshift, 262144 rows.
// Input  row: 64 complex as interleaved f32 (even=re, odd=im) == float2[64].
// Output row: same layout, out[k] = FFT(x)[(k+32) % 64]  (roll by N/2 == k^32).
//
// Decomposition: n = 8*n1 + n2, k = k1 + 8*k2.
//   X[k1+8k2] = sum_{n2} W64^{n2*k1} * W8^{n2*k2} * ( sum_{n1} x[8n1+n2] W8^{n1*k1} )
// 8 threads per FFT: thread n2 does inner DFT8 over n1 + twiddle; 8x8
// transpose via LDS; thread (as k1) does outer DFT8 over n2.

struct c2 { float re, im; };

__device__ __forceinline__ c2 cadd(c2 a, c2 b) { return {a.re + b.re, a.im + b.im}; }
__device__ __forceinline__ c2 csub(c2 a, c2 b) { return {a.re - b.re, a.im - b.im}; }

// In-place 8-point DFT (forward, W = e^{-2pi i/8}), natural-order output.
__device__ __forceinline__ void dft8(c2* v) {
    const float C = 0.70710678118654752f; // sqrt(2)/2
    c2 t0 = cadd(v[0], v[4]);
    c2 t1 = cadd(v[1], v[5]);
    c2 t2 = cadd(v[2], v[6]);
    c2 t3 = cadd(v[3], v[7]);
    c2 u0 = csub(v[0], v[4]);
    c2 u1 = csub(v[1], v[5]);  u1 = {C * (u1.re + u1.im), C * (u1.im - u1.re)};   // * W8^1
    c2 u2 = csub(v[2], v[6]);  u2 = {u2.im, -u2.re};                               // * W8^2 (-i)
    c2 u3 = csub(v[3], v[7]);  u3 = {C * (u3.im - u3.re), -C * (u3.re + u3.im)};   // * W8^3
    // DFT4 on t -> even outputs
    c2 s0 = cadd(t0, t2), s1 = cadd(t1, t3);
    c2 d0 = csub(t0, t2), d1 = csub(t1, t3);  d1 = {d1.im, -d1.re};                // * -i
    v[0] = cadd(s0, s1);
    v[4] = csub(s0, s1);
    v[2] = cadd(d0, d1);
    v[6] = csub(d0, d1);
    // DFT4 on u -> odd outputs
    c2 s2 = cadd(u0, u2), s3 = cadd(u1, u3);
    c2 d2 = csub(u0, u2), d3 = csub(u1, u3);  d3 = {d3.im, -d3.re};                // * -i
    v[1] = cadd(s2, s3);
    v[5] = csub(s2, s3);
    v[3] = cadd(d2, d3);
    v[7] = csub(d2, d3);
}

#define FFTS_PER_BLOCK 32
#define ROW_PAD 66  // 64 complex + 2 pad: spreads LDS banks (4f offset per row)

// W64^m = exp(-2*pi*i*m/64), m = 0..63. Compile-time table; avoids __sincosf.
__device__ __constant__ float TW_RE[64] = {
     1.00000000e+00f,  9.95184727e-01f,  9.80785280e-01f,  9.56940336e-01f,
     9.23879533e-01f,  8.81921264e-01f,  8.31469612e-01f,  7.73010453e-01f,
     7.07106781e-01f,  6.34393284e-01f,  5.55570233e-01f,  4.71396737e-01f,
     3.82683432e-01f,  2.90284677e-01f,  1.95090322e-01f,  9.80171403e-02f,
     6.12323400e-17f, -9.80171403e-02f, -1.95090322e-01f, -2.90284677e-01f,
    -3.82683432e-01f, -4.71396737e-01f, -5.55570233e-01f, -6.34393284e-01f,
    -7.07106781e-01f, -7.73010453e-01f, -8.31469612e-01f, -8.81921264e-01f,
    -9.23879533e-01f, -9.56940336e-01f, -9.80785280e-01f, -9.95184727e-01f,
    -1.00000000e+00f, -9.95184727e-01f, -9.80785280e-01f, -9.56940336e-01f,
    -9.23879533e-01f, -8.81921264e-01f, -8.31469612e-01f, -7.73010453e-01f,
    -7.07106781e-01f, -6.34393284e-01f, -5.55570233e-01f, -4.71396737e-01f,
    -3.82683432e-01f, -2.90284677e-01f, -1.95090322e-01f, -9.80171403e-02f,
    -1.83697020e-16f,  9.80171403e-02f,  1.95090322e-01f,  2.90284677e-01f,
     3.82683432e-01f,  4.71396737e-01f,  5.55570233e-01f,  6.34393284e-01f,
     7.07106781e-01f,  7.73010453e-01f,  8.31469612e-01f,  8.81921264e-01f,
     9.23879533e-01f,  9.56940336e-01f,  9.80785280e-01f,  9.95184727e-01f,
};
__device__ __constant__ float TW_IM[64] = {
    -0.00000000e+00f, -9.80171403e-02f, -1.95090322e-01f, -2.90284677e-01f,
    -3.82683432e-01f, -4.71396737e-01f, -5.55570233e-01f, -6.34393284e-01f,
    -7.07106781e-01f, -7.73010453e-01f, -8.31469612e-01f, -8.81921264e-01f,
    -9.23879533e-01f, -9.56940336e-01f, -9.80785280e-01f, -9.95184727e-01f,
    -1.00000000e+00f, -9.95184727e-01f, -9.80785280e-01f, -9.56940336e-01f,
    -9.23879533e-01f, -8.81921264e-01f, -8.31469612e-01f, -7.73010453e-01f,
    -7.07106781e-01f, -6.34393284e-01f, -5.55570233e-01f, -4.71396737e-01f,
    -3.82683432e-01f, -2.90284677e-01f, -1.95090322e-01f, -9.80171403e-02f,
    -1.22464680e-16f,  9.80171403e-02f,  1.95090322e-01f,  2.90284677e-01f,
     3.82683432e-01f,  4.71396737e-01f,  5.55570233e-01f,  6.34393284e-01f,
     7.07106781e-01f,  7.73010453e-01f,  8.31469612e-01f,  8.81921264e-01f,
     9.23879533e-01f,  9.56940336e-01f,  9.80785280e-01f,  9.95184727e-01f,
     1.00000000e+00f,  9.95184727e-01f,  9.80785280e-01f,  9.56940336e-01f,
     9.23879533e-01f,  8.81921264e-01f,  8.31469612e-01f,  7.73010453e-01f,
     7.07106781e-01f,  6.34393284e-01f,  5.55570233e-01f,  4.71396737e-01f,
     3.82683432e-01f,  2.90284677e-01f,  1.95090322e-01f,  9.80171403e-02f,
};

__global__ __launch_bounds__(256) void fft64_shift_kernel(
        const float2* __restrict__ in, float2* __restrict__ out) {
    __shared__ float2 B[FFTS_PER_BLOCK][ROW_PAD];

    const int tid = threadIdx.x;
    const int n2  = tid & 7;        // lane-in-group: n2 in phase 1, k1 in phase 2
    const int f   = tid >> 3;       // FFT index within block (wave-local group)
    const long row = (long)blockIdx.x * FFTS_PER_BLOCK + f;

    const float2* __restrict__ src = in + row * 64;

    c2 v[8];
    // Load x[8*n1 + n2] for n1 = 0..7 (8-byte loads; wave covers 8 rows x 64B segments)
    #pragma unroll
    for (int n1 = 0; n1 < 8; ++n1) {
        float2 t = src[8 * n1 + n2];
        v[n1] = {t.x, t.y};
    }

    // Inner DFT8 over n1 -> A[k1]
    dft8(v);

    // Twiddle: A'[k1] = A[k1] * W64^{n2*k1}  (table lookup, index = n2*k1 mod 64)
    #pragma unroll
    for (int k1 = 1; k1 < 8; ++k1) {
        const int m = (n2 * k1) & 63;
        const float c = TW_RE[m], s = TW_IM[m];
        c2 a = v[k1];
        v[k1] = {a.re * c - a.im * s, a.re * s + a.im * c};
    }

    // Transpose through LDS: write A'[k1] at [f][8*k1 + n2]
    #pragma unroll
    for (int k1 = 0; k1 < 8; ++k1)
        B[f][8 * k1 + n2] = make_float2(v[k1].re, v[k1].im);

    __syncthreads();

    // Phase 2: this thread is k1 = n2; read A'[k1, n2] for n2 = 0..7 (contiguous, float4)
    const int k1 = n2;
    const float4* __restrict__ brow = (const float4*)(&B[f][8 * k1]);  // 16B-aligned
    #pragma unroll
    for (int j = 0; j < 4; ++j) {
        float4 q = brow[j];
        v[2 * j]     = {q.x, q.y};
        v[2 * j + 1] = {q.z, q.w};
    }

    // Outer DFT8 over n2 -> X[k1 + 8*k2]
    dft8(v);

    // Store with fftshift: out[k1 + 8*(k2^4)] = X[k1 + 8*k2]
    float2* __restrict__ dst = out + row * 64;
    #pragma unroll
    for (int k2 = 0; k2 < 8; ++k2)
        dst[k1 + 8 * (k2 ^ 4)] = make_float2(v[k2].re, v[k2].im);
}

extern "C" void kernel_launch(void* const* d_in, const int* in_sizes, int n_in,
                              void* d_out, int out_size, void* d_ws, size_t ws_size,
                              hipStream_t stream) {
    const float2* in2 = (const float2*)d_in[0];
    float2* out2 = (float2*)d_out;
    // 4096 * 64 = 262144 rows; 32 rows per block -> 8192 blocks
    const int n_rows = in_sizes[0] / 128;  // 128 floats per row
    const int blocks = n_rows / FFTS_PER_BLOCK;
    fft64_shift_kernel<<<blocks, 256, 0, stream>>>(in2, out2);
}

// Round 8
// 222.175 us; speedup vs baseline: 1.0104x; 1.0104x over previous
//
#include <hip/hip_runtime.h>
#include <hip/hip_bf16.h>

// 64-point complex FFT + fftshift, 262144 rows.
// Input  row: 64 complex as interleaved f32 (even=re, odd=im) == float2[64].
// Output row: same layout, out[k] = FFT(x)[(k+32) % 64]  (roll by N/2 == k^32).
//
// Decomposition: n = 8*n1 + n2, k = k1 + 8*k2.
//   X[k1+8k2] = sum_{n2} W64^{n2*k1} * W8^{n2*k2} * ( sum_{n1} x[8n1+n2] W8^{n1*k1} )
// 8 threads per FFT: thread n2 does inner DFT8 over n1 + twiddle; 8x8
// transpose via LDS; thread (as k1) does outer DFT8 over n2.
//
// v2b (R7/R8): nontemporal builtins need native clang vector types, not
// HIP_vector_type -- use ext_vector_type(2) float for the streaming accesses.

typedef float v2f __attribute__((ext_vector_type(2)));

struct c2 { float re, im; };

__device__ __forceinline__ c2 cadd(c2 a, c2 b) { return {a.re + b.re, a.im + b.im}; }
__device__ __forceinline__ c2 csub(c2 a, c2 b) { return {a.re - b.re, a.im - b.im}; }
__device__ __forceinline__ c2 cmul(c2 a, c2 b) {
    return {a.re * b.re - a.im * b.im, a.re * b.im + a.im * b.re};
}

// In-place 8-point DFT (forward, W = e^{-2pi i/8}), natural-order output.
__device__ __forceinline__ void dft8(c2* v) {
    const float C = 0.70710678118654752f; // sqrt(2)/2
    c2 t0 = cadd(v[0], v[4]);
    c2 t1 = cadd(v[1], v[5]);
    c2 t2 = cadd(v[2], v[6]);
    c2 t3 = cadd(v[3], v[7]);
    c2 u0 = csub(v[0], v[4]);
    c2 u1 = csub(v[1], v[5]);  u1 = {C * (u1.re + u1.im), C * (u1.im - u1.re)};   // * W8^1
    c2 u2 = csub(v[2], v[6]);  u2 = {u2.im, -u2.re};                               // * W8^2 (-i)
    c2 u3 = csub(v[3], v[7]);  u3 = {C * (u3.im - u3.re), -C * (u3.re + u3.im)};   // * W8^3
    // DFT4 on t -> even outputs
    c2 s0 = cadd(t0, t2), s1 = cadd(t1, t3);
    c2 d0 = csub(t0, t2), d1 = csub(t1, t3);  d1 = {d1.im, -d1.re};                // * -i
    v[0] = cadd(s0, s1);
    v[4] = csub(s0, s1);
    v[2] = cadd(d0, d1);
    v[6] = csub(d0, d1);
    // DFT4 on u -> odd outputs
    c2 s2 = cadd(u0, u2), s3 = cadd(u1, u3);
    c2 d2 = csub(u0, u2), d3 = csub(u1, u3);  d3 = {d3.im, -d3.re};                // * -i
    v[1] = cadd(s2, s3);
    v[5] = csub(s2, s3);
    v[3] = cadd(d2, d3);
    v[7] = csub(d2, d3);
}

#define FFTS_PER_BLOCK 32
#define ROW_PAD 66  // 64 complex + 2 pad: spreads LDS banks (4f offset per row)

__global__ __launch_bounds__(256) void fft64_shift_kernel(
        const float2* __restrict__ in, float2* __restrict__ out) {
    __shared__ float2 B[FFTS_PER_BLOCK][ROW_PAD];

    const int tid = threadIdx.x;
    const int n2  = tid & 7;        // lane-in-group: n2 in phase 1, k1 in phase 2
    const int f   = tid >> 3;       // FFT index within block (wave-local group)
    const long row = (long)blockIdx.x * FFTS_PER_BLOCK + f;

    const v2f* __restrict__ src = (const v2f*)(in + row * 64);

    c2 v[8];
    // Load x[8*n1 + n2] for n1 = 0..7. Per wave-instruction: 8 rows x 64B
    // contiguous chunks; across the 8 instructions every 512B row is dense.
    #pragma unroll
    for (int n1 = 0; n1 < 8; ++n1) {
        v2f t = __builtin_nontemporal_load(&src[8 * n1 + n2]);
        v[n1] = {t.x, t.y};
    }

    // Inner DFT8 over n1 -> A[k1]
    dft8(v);

    // Twiddle: A'[k1] = A[k1] * W64^{n2*k1}.
    // w1 = W64^{n2} from one __sincosf; w_{k} = w_{k-1} * w1 recurrence
    // (7 steps, rel-err ~ 7 ulp -- far inside the bf16-ref threshold).
    {
        float s1, c1;
        __sincosf(-0.09817477042468103f * (float)n2, &s1, &c1);
        const c2 w1 = {c1, s1};
        c2 w = w1;
        #pragma unroll
        for (int k1 = 1; k1 < 8; ++k1) {
            v[k1] = cmul(v[k1], w);
            w = cmul(w, w1);
        }
    }

    // Transpose through LDS: write A'[k1] at [f][8*k1 + n2]
    #pragma unroll
    for (int k1 = 0; k1 < 8; ++k1)
        B[f][8 * k1 + n2] = make_float2(v[k1].re, v[k1].im);

    __syncthreads();

    // Phase 2: this thread is k1 = n2; read A'[k1, n2] for n2 = 0..7
    // (contiguous float4, start offset f*528 + k1*64 is 16B-aligned,
    //  bank-quad spread is uniform -> conflict-free)
    const int k1 = n2;
    const float4* __restrict__ brow = (const float4*)(&B[f][8 * k1]);
    #pragma unroll
    for (int j = 0; j < 4; ++j) {
        float4 q = brow[j];
        v[2 * j]     = {q.x, q.y};
        v[2 * j + 1] = {q.z, q.w};
    }

    // Outer DFT8 over n2 -> X[k1 + 8*k2]
    dft8(v);

    // Store with fftshift: out[k1 + 8*(k2^4)] = X[k1 + 8*k2]
    v2f* __restrict__ dst = (v2f*)(out + row * 64);
    #pragma unroll
    for (int k2 = 0; k2 < 8; ++k2) {
        v2f t;
        t.x = v[k2].re;
        t.y = v[k2].im;
        __builtin_nontemporal_store(t, &dst[k1 + 8 * (k2 ^ 4)]);
    }
}

extern "C" void kernel_launch(void* const* d_in, const int* in_sizes, int n_in,
                              void* d_out, int out_size, void* d_ws, size_t ws_size,
                              hipStream_t stream) {
    const float2* in2 = (const float2*)d_in[0];
    float2* out2 = (float2*)d_out;
    // 4096 * 64 = 262144 rows; 32 rows per block -> 8192 blocks
    const int n_rows = in_sizes[0] / 128;  // 128 floats per row
    const int blocks = n_rows / FFTS_PER_BLOCK;
    fft64_shift_kernel<<<blocks, 256, 0, stream>>>(in2, out2);
}

// Round 11
// 218.076 us; speedup vs baseline: 1.0293x; 1.0188x over previous
//
#include <hip/hip_runtime.h>
#include <hip/hip_bf16.h>

// 64-point complex FFT + fftshift, 262144 rows.
// Input  row: 64 complex interleaved f32 == float2[64]. Output: same layout,
// out[k] = FFT(x)[(k+32) % 64]  (roll by N/2 == k^32).
//
// v3 (R9/R10/R11): all GLOBAL accesses are float4 (16B/lane, dwordx4) via an
// LDS sandwich; the verified radix-8x8 core (8 threads/FFT) is unchanged.
//   step1: global float4 -> LDS (linear)            [barrier]
//   step2: LDS -> regs (stride-8 complex) ; DFT8 ; twiddle   [barrier]
//          regs -> LDS (transposed [f][8k1+n2])     [barrier]
//   step3: LDS -> regs (contig float4) ; DFT8       [barrier]
//          regs -> LDS ([f][k1+8*(k2^4)], fftshift) [barrier]
//   step4: LDS -> global float4 (linear, nontemporal)

typedef float v4f __attribute__((ext_vector_type(4)));

struct c2 { float re, im; };

__device__ __forceinline__ c2 cadd(c2 a, c2 b) { return {a.re + b.re, a.im + b.im}; }
__device__ __forceinline__ c2 csub(c2 a, c2 b) { return {a.re - b.re, a.im - b.im}; }
__device__ __forceinline__ c2 cmul(c2 a, c2 b) {
    return {a.re * b.re - a.im * b.im, a.re * b.im + a.im * b.re};
}

// In-place 8-point DFT (forward, W = e^{-2pi i/8}), natural-order output.
__device__ __forceinline__ void dft8(c2* v) {
    const float C = 0.70710678118654752f; // sqrt(2)/2
    c2 t0 = cadd(v[0], v[4]);
    c2 t1 = cadd(v[1], v[5]);
    c2 t2 = cadd(v[2], v[6]);
    c2 t3 = cadd(v[3], v[7]);
    c2 u0 = csub(v[0], v[4]);
    c2 u1 = csub(v[1], v[5]);  u1 = {C * (u1.re + u1.im), C * (u1.im - u1.re)};   // * W8^1
    c2 u2 = csub(v[2], v[6]);  u2 = {u2.im, -u2.re};                               // * W8^2 (-i)
    c2 u3 = csub(v[3], v[7]);  u3 = {C * (u3.im - u3.re), -C * (u3.re + u3.im)};   // * W8^3
    c2 s0 = cadd(t0, t2), s1 = cadd(t1, t3);
    c2 d0 = csub(t0, t2), d1 = csub(t1, t3);  d1 = {d1.im, -d1.re};                // * -i
    v[0] = cadd(s0, s1);
    v[4] = csub(s0, s1);
    v[2] = cadd(d0, d1);
    v[6] = csub(d0, d1);
    c2 s2 = cadd(u0, u2), s3 = cadd(u1, u3);
    c2 d2 = csub(u0, u2), d3 = csub(u1, u3);  d3 = {d3.im, -d3.re};                // * -i
    v[1] = cadd(s2, s3);
    v[5] = csub(s2, s3);
    v[3] = cadd(d2, d3);
    v[7] = csub(d2, d3);
}

#define FFTS_PER_BLOCK 32
#define ROW_PAD 66  // complex pitch per row; 66*8B = 528B (16B-aligned rows)

__global__ __launch_bounds__(256) void fft64_shift_kernel(
        const float2* __restrict__ in, float2* __restrict__ out) {
    __shared__ float2 S[FFTS_PER_BLOCK][ROW_PAD];

    const int tid = threadIdx.x;
    const int n2  = tid & 7;        // lane-in-group: n2 in phase 1, k1 in phase 2
    const int f   = tid >> 3;       // FFT index within block

    // ---- step 1: global -> LDS, linear float4 (block chunk = 1024 float4) ----
    const v4f* __restrict__ in4 =
        (const v4f*)(in + (long)blockIdx.x * FFTS_PER_BLOCK * 64);
    #pragma unroll
    for (int i = 0; i < 4; ++i) {
        const int q = tid + 256 * i;          // float4 index in chunk
        v4f t = __builtin_nontemporal_load(&in4[q]);
        const int r = q >> 5;                 // row (32 float4 per row)
        const int c = q & 31;                 // float4 col within row
        *(v4f*)(&S[r][2 * c]) = t;            // 16B-aligned LDS write
    }
    __syncthreads();

    // ---- step 2a: LDS -> regs, x[8*n1 + n2] of row f ----
    c2 v[8];
    #pragma unroll
    for (int n1 = 0; n1 < 8; ++n1) {
        float2 t = S[f][8 * n1 + n2];
        v[n1] = {t.x, t.y};
    }

    // Inner DFT8 over n1 -> A[k1]
    dft8(v);

    // Twiddle: A'[k1] = A[k1] * W64^{n2*k1} (sincos + recurrence)
    {
        float s1, c1;
        __sincosf(-0.09817477042468103f * (float)n2, &s1, &c1);
        const c2 w1 = {c1, s1};
        c2 w = w1;
        #pragma unroll
        for (int k1 = 1; k1 < 8; ++k1) {
            v[k1] = cmul(v[k1], w);
            w = cmul(w, w1);
        }
    }

    __syncthreads();   // all step-2a reads done before transpose overwrites S

    // ---- step 2b: regs -> LDS transposed: A'[k1] at [f][8*k1 + n2] ----
    #pragma unroll
    for (int k1 = 0; k1 < 8; ++k1)
        S[f][8 * k1 + n2] = make_float2(v[k1].re, v[k1].im);
    __syncthreads();

    // ---- step 3a: LDS -> regs, contiguous float4 at [f][8*k1'] (k1' = n2) ----
    {
        const v4f* brow = (const v4f*)(&S[f][8 * n2]);
        #pragma unroll
        for (int j = 0; j < 4; ++j) {
            v4f q = brow[j];
            v[2 * j]     = {q.x, q.y};
            v[2 * j + 1] = {q.z, q.w};
        }
    }

    // Outer DFT8 over n2 -> X[k1' + 8*k2]
    dft8(v);

    __syncthreads();   // all step-3a reads done before shift-scatter overwrites S

    // ---- step 3b: regs -> LDS with fftshift: [f][k1' + 8*(k2^4)] ----
    #pragma unroll
    for (int k2 = 0; k2 < 8; ++k2)
        S[f][n2 + 8 * (k2 ^ 4)] = make_float2(v[k2].re, v[k2].im);
    __syncthreads();

    // ---- step 4: LDS -> global, linear float4, nontemporal ----
    v4f* __restrict__ out4 = (v4f*)(out + (long)blockIdx.x * FFTS_PER_BLOCK * 64);
    #pragma unroll
    for (int i = 0; i < 4; ++i) {
        const int q = tid + 256 * i;
        const int r = q >> 5;
        const int c = q & 31;
        v4f t = *(const v4f*)(&S[r][2 * c]);
        __builtin_nontemporal_store(t, &out4[q]);
    }
}

extern "C" void kernel_launch(void* const* d_in, const int* in_sizes, int n_in,
                              void* d_out, int out_size, void* d_ws, size_t ws_size,
                              hipStream_t stream) {
    const float2* in2 = (const float2*)d_in[0];
    float2* out2 = (float2*)d_out;
    // 4096 * 64 = 262144 rows; 32 rows per block -> 8192 blocks
    const int n_rows = in_sizes[0] / 128;  // 128 floats per row
    const int blocks = n_rows / FFTS_PER_BLOCK;
    fft64_shift_kernel<<<blocks, 256, 0, stream>>>(in2, out2);
}